// Round 1
// baseline (780.332 us; speedup 1.0000x reference)
//
#include <hip/hip_runtime.h>
#include <hip/hip_bf16.h>

// Dims: B=2, S=12, N=256, E=512, H=8, dk=64, SH=96
// Pipeline:
//  k0: weights -> bf16, transposed to [n][k]
//  k1: input_Q/K/V [B,E,N,S] -> xq/xk/xv [B,S,N,E] fp32
//  k2: Q/K/V = x @ W   (bf16 MFMA, out bf16 [B,S,N,E])
//  k3: EbX = input_E @ We, written as ebT[(b,h,s)][n][m] bf16 (plane-transposed)
//  k4: per (b,s,h,n-tile): scores=QK^T*0.125, e_=scores*Eb (-> eT[(b,h,s)][m][n]),
//      softmax(e_) over m, ctx = P@V  (fp32 ctx [B,S,N,E])
//  k5: ctxln = LN(ctx@Wo + bo + xq)   (fused GEMM+LN, full 512-col rows per block)
//  k6: out2 = LN(e_t@Wfe + bfe + input_E)  (fused GEMM+LN)
//  k7: out1[b,e,n,s] = ctxln[b,s,n,e]

typedef float  f32x4   __attribute__((ext_vector_type(4)));
typedef short  short8  __attribute__((ext_vector_type(8)));
typedef short  short4v __attribute__((ext_vector_type(4)));

__device__ __forceinline__ f32x4 MFMA(short8 a, short8 b, f32x4 c) {
  return __builtin_amdgcn_mfma_f32_16x16x32_bf16(a, b, c, 0, 0, 0);
}
__device__ __forceinline__ short f2b(float f) {
  union { __hip_bfloat16 h; short u; } v; v.h = __float2bfloat16(f); return v.u;
}
__device__ __forceinline__ float b2f(short x) {
  union { __hip_bfloat16 h; short u; } v; v.u = x; return __bfloat162float(v.h);
}

// ---------------- k0: weight prep ----------------
__global__ __launch_bounds__(256) void k0_prep(
    const float* __restrict__ Wq, const float* __restrict__ Wk,
    const float* __restrict__ Wv, const float* __restrict__ Wo,
    const float* __restrict__ We, const float* __restrict__ Wfe,
    short* __restrict__ WqT, short* __restrict__ WkT, short* __restrict__ WvT,
    short* __restrict__ WoT, short* __restrict__ WeT, short* __restrict__ WfeT)
{
  int t = blockIdx.x * 256 + threadIdx.x;
  if (t < 512 * 512) {           // [512n][512k] <- W[k][n]
    int n = t >> 9, k = t & 511;
    int s = k * 512 + n;
    WqT[t] = f2b(Wq[s]); WkT[t] = f2b(Wk[s]); WvT[t] = f2b(Wv[s]); WoT[t] = f2b(Wo[s]);
  }
  if (t < 96 * 512) {            // WeT [96n][512k] <- We[k][n], n<96
    int n = t >> 9, k = t & 511;
    WeT[t] = f2b(We[k * 96 + n]);
  }
  if (t < 512 * 96) {            // WfeT [512n][96k] <- Wfe[k][n], k<96
    int n = t / 96, k = t - n * 96;
    WfeT[t] = f2b(Wfe[k * 512 + n]);
  }
}

// ---------------- k1: QKV input transpose ----------------
__global__ __launch_bounds__(256) void k1_txpose(
    const float* __restrict__ inQ, const float* __restrict__ inK, const float* __restrict__ inV,
    float* __restrict__ xq, float* __restrict__ xk, float* __restrict__ xv)
{
  __shared__ float tile[512 * 12];
  int b = blockIdx.x >> 8, n = blockIdx.x & 255;
  const float* src[3] = { inQ, inK, inV };
  float* dst[3] = { xq, xk, xv };
  for (int a = 0; a < 3; a++) {
    const float* sp = src[a] + (size_t)b * 1572864 + (size_t)n * 12; // + e*3072 + s
    for (int i = threadIdx.x; i < 6144; i += 256) {
      int e = i / 12, s = i - e * 12;
      tile[i] = sp[e * 3072 + s];
    }
    __syncthreads();
    float* dp = dst[a] + (size_t)b * 1572864 + (size_t)n * 512;      // + s*131072 + e
    for (int i = threadIdx.x; i < 6144; i += 256) {
      int s = i >> 9, e = i & 511;
      dp[s * 131072 + e] = tile[e * 12 + s];
    }
    __syncthreads();
  }
}

// ---------------- k2: projections (128x128 tile, K-loop 64) ----------------
__global__ __launch_bounds__(256) void k2_proj(
    const float* __restrict__ xq, const float* __restrict__ xk, const float* __restrict__ xv,
    const short* __restrict__ WqT, const short* __restrict__ WkT, const short* __restrict__ WvT,
    short* __restrict__ Qb, short* __restrict__ Kb, short* __restrict__ Vb)
{
  __shared__ short Al[128][72];
  __shared__ short Bl[128][72];
  int z = blockIdx.z;
  const float* A  = (z == 0) ? xq  : (z == 1) ? xk  : xv;
  const short* Wt = (z == 0) ? WqT : (z == 1) ? WkT : WvT;
  short*       Ob = (z == 0) ? Qb  : (z == 1) ? Kb  : Vb;
  int m0 = blockIdx.x * 128, n0 = blockIdx.y * 128;
  int t = threadIdx.x, l = t & 63, w = t >> 6;
  int lr = l & 15, lg = l >> 4;
  int row_off = (w & 1) * 64, col_off = (w >> 1) * 64;
  f32x4 acc[4][4];
  for (int i = 0; i < 4; i++) for (int j = 0; j < 4; j++) acc[i][j] = (f32x4){0.f,0.f,0.f,0.f};
  for (int k0 = 0; k0 < 512; k0 += 64) {
    __syncthreads();
    for (int i = t; i < 2048; i += 256) {       // A: 128x64 fp32->bf16
      int r = i >> 4, c4 = (i & 15) * 4;
      float4 v = *(const float4*)(A + (size_t)(m0 + r) * 512 + k0 + c4);
      short4v sv = { f2b(v.x), f2b(v.y), f2b(v.z), f2b(v.w) };
      *(short4v*)&Al[r][c4] = sv;
    }
    for (int i = t; i < 1024; i += 256) {       // B: WT rows n0..n0+128, k-chunk
      int r = i >> 3, c8 = (i & 7) * 8;
      *(int4*)&Bl[r][c8] = *(const int4*)(Wt + (size_t)(n0 + r) * 512 + k0 + c8);
    }
    __syncthreads();
    for (int ks = 0; ks < 2; ks++) {
      short8 a[4], bb[4];
      for (int rs = 0; rs < 4; rs++) a[rs]  = *(const short8*)&Al[row_off + rs*16 + lr][ks*32 + lg*8];
      for (int cs = 0; cs < 4; cs++) bb[cs] = *(const short8*)&Bl[col_off + cs*16 + lr][ks*32 + lg*8];
      for (int rs = 0; rs < 4; rs++)
        for (int cs = 0; cs < 4; cs++)
          acc[rs][cs] = MFMA(a[rs], bb[cs], acc[rs][cs]);
    }
  }
  for (int rs = 0; rs < 4; rs++)
    for (int cs = 0; cs < 4; cs++) {
      int row = m0 + row_off + rs * 16 + lg * 4;
      int col = n0 + col_off + cs * 16 + lr;
      for (int r = 0; r < 4; r++)
        Ob[(size_t)(row + r) * 512 + col] = f2b(acc[rs][cs][r]);
    }
}

// ---------------- k3: EbX = input_E @ We -> ebT[(b*96+h*12+s)][n][m] bf16 ----------------
__global__ __launch_bounds__(256) void k3_ebx(
    const float* __restrict__ inE, const short* __restrict__ WeT, short* __restrict__ ebT)
{
  __shared__ short Al[128][72];
  __shared__ short Bl[96][72];
  int R0 = blockIdx.x * 128;
  int b = R0 >> 16;
  int Rl0 = R0 & 65535;
  int t = threadIdx.x, l = t & 63, w = t >> 6;
  int lr = l & 15, lg = l >> 4;
  f32x4 acc[2][6];
  for (int i = 0; i < 2; i++) for (int j = 0; j < 6; j++) acc[i][j] = (f32x4){0.f,0.f,0.f,0.f};
  for (int k0 = 0; k0 < 512; k0 += 64) {
    __syncthreads();
    for (int i = t; i < 2048; i += 256) {
      int r = i >> 4, c4 = (i & 15) * 4;
      float4 v = *(const float4*)(inE + (size_t)(R0 + r) * 512 + k0 + c4);
      short4v sv = { f2b(v.x), f2b(v.y), f2b(v.z), f2b(v.w) };
      *(short4v*)&Al[r][c4] = sv;
    }
    for (int i = t; i < 768; i += 256) {
      int r = i >> 3, c8 = (i & 7) * 8;
      *(int4*)&Bl[r][c8] = *(const int4*)(WeT + (size_t)r * 512 + k0 + c8);
    }
    __syncthreads();
    for (int ks = 0; ks < 2; ks++) {
      short8 a0 = *(const short8*)&Al[w*32 + lr][ks*32 + lg*8];
      short8 a1 = *(const short8*)&Al[w*32 + 16 + lr][ks*32 + lg*8];
      for (int cs = 0; cs < 6; cs++) {
        short8 bb = *(const short8*)&Bl[cs*16 + lr][ks*32 + lg*8];
        acc[0][cs] = MFMA(a0, bb, acc[0][cs]);
        acc[1][cs] = MFMA(a1, bb, acc[1][cs]);
      }
    }
  }
  // lane's 4 regs are 4 consecutive rows (fixed col) -> 8B contiguous stores
  for (int rs = 0; rs < 2; rs++)
    for (int cs = 0; cs < 6; cs++) {
      int col = cs * 16 + lr;
      int rowl = Rl0 + w * 32 + rs * 16 + lg * 4;
      short4v sv = { f2b(acc[rs][cs][0]), f2b(acc[rs][cs][1]),
                     f2b(acc[rs][cs][2]), f2b(acc[rs][cs][3]) };
      *(short4v*)(ebT + ((size_t)(b * 96 + col) << 16) + rowl) = sv;
    }
}

// ---------------- k4: fused attention ----------------
__global__ __launch_bounds__(256) void k4_attn(
    const short* __restrict__ Qb, const short* __restrict__ Kb, const short* __restrict__ Vb,
    const short* __restrict__ ebT, short* __restrict__ eT, float* __restrict__ ctx)
{
  __shared__ __align__(16) char smem[150528];
  short (*Kl)[72]   = (short(*)[72]) (smem);            // 256x72   K[m][d]
  short (*Vt)[264]  = (short(*)[264])(smem + 36864);    // 64x264   V^T[d][m]
  short (*Et)[72]   = (short(*)[72]) (smem + 70656);    // 256x72   e[m][n_local]
  short (*Ql)[72]   = (short(*)[72]) (smem + 107520);   // 64x72    Q[n_local][d] (phase 1)
  short (*Ebl)[264] = (short(*)[264])(smem + 116736);   // 64x264   Eb[n_local][m] (phase 1)
  short (*Pl)[264]  = (short(*)[264])(smem + 107520);   // 64x264   P[n_local][m] (phase 2)

  int n0 = blockIdx.x * 64;
  int s = blockIdx.y >> 3, h = blockIdx.y & 7;
  int b = blockIdx.z;
  int t = threadIdx.x, l = t & 63, w = t >> 6;
  int lr = l & 15, lg = l >> 4;

  size_t qkvBase = ((size_t)(b * 12 + s) * 256) * 512 + h * 64;
  size_t plane = (size_t)(b * 96 + h * 12 + s) << 16;

  for (int i = t; i < 512; i += 256) {          // Q strip 64x64
    int r = i >> 3, c8 = (i & 7) * 8;
    *(int4*)&Ql[r][c8] = *(const int4*)(Qb + qkvBase + (size_t)(n0 + r) * 512 + c8);
  }
  for (int i = t; i < 2048; i += 256) {         // K full 256x64
    int r = i >> 3, c8 = (i & 7) * 8;
    *(int4*)&Kl[r][c8] = *(const int4*)(Kb + qkvBase + (size_t)r * 512 + c8);
  }
  for (int i = t; i < 2048; i += 256) {         // V -> V^T
    int m = i >> 3, c8 = (i & 7) * 8;
    short8 v = *(const short8*)(Vb + qkvBase + (size_t)m * 512 + c8);
    for (int j = 0; j < 8; j++) Vt[c8 + j][m] = v[j];
  }
  for (int i = t; i < 2048; i += 256) {         // Eb strip 64x256
    int r = i >> 5, c8 = (i & 31) * 8;
    *(int4*)&Ebl[r][c8] = *(const int4*)(ebT + plane + (size_t)(n0 + r) * 256 + c8);
  }
  __syncthreads();

  // scores = Q K^T (wave w: rows w*16..w*16+16, all 256 m)
  f32x4 acc[16];
  for (int i = 0; i < 16; i++) acc[i] = (f32x4){0.f,0.f,0.f,0.f};
  short8 a0 = *(const short8*)&Ql[w*16 + lr][lg*8];
  short8 a1 = *(const short8*)&Ql[w*16 + lr][32 + lg*8];
  for (int mt = 0; mt < 16; mt++) {
    short8 b0 = *(const short8*)&Kl[mt*16 + lr][lg*8];
    short8 b1 = *(const short8*)&Kl[mt*16 + lr][32 + lg*8];
    acc[mt] = MFMA(a0, b0, acc[mt]);
    acc[mt] = MFMA(a1, b1, acc[mt]);
  }

  // e_ = scores * 0.125 * Eb ; stash transposed into Et[m][n_local]
  int nlb = w * 16 + lg * 4;
  for (int mt = 0; mt < 16; mt++) {
    int m = mt * 16 + lr;
    f32x4 e;
    for (int r = 0; r < 4; r++)
      e[r] = acc[mt][r] * 0.125f * b2f(Ebl[nlb + r][m]);
    acc[mt] = e;
    short4v sv = { f2b(e[0]), f2b(e[1]), f2b(e[2]), f2b(e[3]) };
    *(short4v*)&Et[m][nlb] = sv;
  }

  // softmax over m (rows live in 16-lane groups)
  f32x4 rmax = acc[0];
  for (int mt = 1; mt < 16; mt++)
    for (int r = 0; r < 4; r++) rmax[r] = fmaxf(rmax[r], acc[mt][r]);
  for (int mask = 1; mask < 16; mask <<= 1)
    for (int r = 0; r < 4; r++) rmax[r] = fmaxf(rmax[r], __shfl_xor(rmax[r], mask));
  f32x4 rsum = (f32x4){0.f,0.f,0.f,0.f};
  for (int mt = 0; mt < 16; mt++)
    for (int r = 0; r < 4; r++) {
      float p = __expf(acc[mt][r] - rmax[r]);
      acc[mt][r] = p; rsum[r] += p;
    }
  for (int mask = 1; mask < 16; mask <<= 1)
    for (int r = 0; r < 4; r++) rsum[r] += __shfl_xor(rsum[r], mask);
  f32x4 rinv;
  for (int r = 0; r < 4; r++) rinv[r] = 1.f / rsum[r];

  __syncthreads();   // Et complete; Ql/Ebl dead -> reuse as Pl

  for (int mt = 0; mt < 16; mt++) {
    int m = mt * 16 + lr;
    for (int r = 0; r < 4; r++)
      Pl[nlb + r][m] = f2b(acc[mt][r] * rinv[r]);
  }
  {  // cooperative coalesced e_ store: eT[plane][m][n0..n0+64]
    int m = t;
    const short* er = &Et[m][0];
    short* gp = eT + plane + (size_t)m * 256 + n0;
    for (int j = 0; j < 8; j++)
      *(int4*)(gp + j * 8) = *(const int4*)(er + j * 8);
  }
  __syncthreads();

  // ctx = P @ V
  f32x4 acc2[4];
  for (int i = 0; i < 4; i++) acc2[i] = (f32x4){0.f,0.f,0.f,0.f};
  for (int kk = 0; kk < 8; kk++) {
    short8 pa = *(const short8*)&Pl[w*16 + lr][kk*32 + lg*8];
    for (int dt = 0; dt < 4; dt++) {
      short8 vb = *(const short8*)&Vt[dt*16 + lr][kk*32 + lg*8];
      acc2[dt] = MFMA(pa, vb, acc2[dt]);
    }
  }
  for (int dt = 0; dt < 4; dt++)
    for (int r = 0; r < 4; r++)
      ctx[qkvBase + (size_t)(n0 + nlb + r) * 512 + dt * 16 + lr] = acc2[dt][r];
}

// ---------------- k5: ctxln = LN(ctx@Wo + bo + xq) ----------------
__global__ __launch_bounds__(512) void k5_ctxo(
    const float* __restrict__ ctx, const short* __restrict__ WoT,
    const float* __restrict__ bo, const float* __restrict__ xq,
    const float* __restrict__ gamma, const float* __restrict__ beta,
    float* __restrict__ ctxln)
{
  __shared__ short Al[64][72];
  __shared__ short Bl[512][72];
  __shared__ float red[64][2][2];
  int R0 = blockIdx.x * 64;
  int t = threadIdx.x, l = t & 63, w = t >> 6;
  int lr = l & 15, lg = l >> 4;
  int rowg = w & 3, colg = w >> 2;
  f32x4 acc[16];
  for (int i = 0; i < 16; i++) acc[i] = (f32x4){0.f,0.f,0.f,0.f};
  for (int k0 = 0; k0 < 512; k0 += 64) {
    __syncthreads();
    for (int i = t; i < 1024; i += 512) {
      int r = i >> 4, c4 = (i & 15) * 4;
      float4 v = *(const float4*)(ctx + (size_t)(R0 + r) * 512 + k0 + c4);
      short4v sv = { f2b(v.x), f2b(v.y), f2b(v.z), f2b(v.w) };
      *(short4v*)&Al[r][c4] = sv;
    }
    for (int i = t; i < 4096; i += 512) {
      int r = i >> 3, c8 = (i & 7) * 8;
      *(int4*)&Bl[r][c8] = *(const int4*)(WoT + (size_t)r * 512 + k0 + c8);
    }
    __syncthreads();
    for (int ks = 0; ks < 2; ks++) {
      short8 a = *(const short8*)&Al[rowg*16 + lr][ks*32 + lg*8];
      for (int ct = 0; ct < 16; ct++) {
        short8 bb = *(const short8*)&Bl[colg*256 + ct*16 + lr][ks*32 + lg*8];
        acc[ct] = MFMA(a, bb, acc[ct]);
      }
    }
  }
  int rowl = rowg * 16 + lg * 4;
  float ysum[4] = {0,0,0,0}, ysq[4] = {0,0,0,0};
  for (int ct = 0; ct < 16; ct++) {
    int col = colg * 256 + ct * 16 + lr;
    for (int r = 0; r < 4; r++) {
      float y = acc[ct][r] + bo[col] + xq[(size_t)(R0 + rowl + r) * 512 + col];
      acc[ct][r] = y;
      ysum[r] += y; ysq[r] += y * y;
    }
  }
  for (int mask = 1; mask < 16; mask <<= 1)
    for (int r = 0; r < 4; r++) {
      ysum[r] += __shfl_xor(ysum[r], mask);
      ysq[r]  += __shfl_xor(ysq[r], mask);
    }
  if (lr == 0)
    for (int r = 0; r < 4; r++) { red[rowl + r][colg][0] = ysum[r]; red[rowl + r][colg][1] = ysq[r]; }
  __syncthreads();
  for (int r = 0; r < 4; r++) {
    float sm = red[rowl + r][0][0] + red[rowl + r][1][0];
    float sq = red[rowl + r][0][1] + red[rowl + r][1][1];
    float mean = sm * (1.f / 512.f);
    float var  = sq * (1.f / 512.f) - mean * mean;
    float rstd = rsqrtf(var + 1e-5f);
    for (int ct = 0; ct < 16; ct++) {
      int col = colg * 256 + ct * 16 + lr;
      ctxln[(size_t)(R0 + rowl + r) * 512 + col] =
          (acc[ct][r] - mean) * rstd * gamma[col] + beta[col];
    }
  }
}

// ---------------- k6: out2 = LN(e_t@Wfe + bfe + input_E) ----------------
__global__ __launch_bounds__(512) void k6_eout(
    const short* __restrict__ eT, const short* __restrict__ WfeT,
    const float* __restrict__ bfe, const float* __restrict__ inE,
    const float* __restrict__ gamma, const float* __restrict__ beta,
    float* __restrict__ out2)
{
  __shared__ short Al[64][104];
  __shared__ short Bl[512][104];
  __shared__ float red[64][2][2];
  int R0 = blockIdx.x * 64;
  int b = blockIdx.x >> 10;
  int Rl0 = R0 & 65535;
  int t = threadIdx.x, l = t & 63, w = t >> 6;
  int lr = l & 15, lg = l >> 4;
  int rowg = w & 3, colg = w >> 2;
  // A[row][k] = eT[(b*96 + (k%8)*12 + k/8)][Rl0+row]   (k = s*8+h)
  for (int i = t; i < 768; i += 512) {
    int k = i >> 3, seg = (i & 7) * 8;
    int plane = b * 96 + (k & 7) * 12 + (k >> 3);
    short8 v = *(const short8*)(eT + ((size_t)plane << 16) + Rl0 + seg);
    for (int j = 0; j < 8; j++) Al[seg + j][k] = v[j];
  }
  for (int i = t; i < 6144; i += 512) {
    int r = i / 12, c8 = (i - r * 12) * 8;
    *(int4*)&Bl[r][c8] = *(const int4*)(WfeT + (size_t)r * 96 + c8);
  }
  __syncthreads();
  f32x4 acc[16];
  for (int i = 0; i < 16; i++) acc[i] = (f32x4){0.f,0.f,0.f,0.f};
  for (int ks = 0; ks < 3; ks++) {
    short8 a = *(const short8*)&Al[rowg*16 + lr][ks*32 + lg*8];
    for (int ct = 0; ct < 16; ct++) {
      short8 bb = *(const short8*)&Bl[colg*256 + ct*16 + lr][ks*32 + lg*8];
      acc[ct] = MFMA(a, bb, acc[ct]);
    }
  }
  int rowl = rowg * 16 + lg * 4;
  float ysum[4] = {0,0,0,0}, ysq[4] = {0,0,0,0};
  for (int ct = 0; ct < 16; ct++) {
    int col = colg * 256 + ct * 16 + lr;
    for (int r = 0; r < 4; r++) {
      float y = acc[ct][r] + bfe[col] + inE[(size_t)(R0 + rowl + r) * 512 + col];
      acc[ct][r] = y;
      ysum[r] += y; ysq[r] += y * y;
    }
  }
  for (int mask = 1; mask < 16; mask <<= 1)
    for (int r = 0; r < 4; r++) {
      ysum[r] += __shfl_xor(ysum[r], mask);
      ysq[r]  += __shfl_xor(ysq[r], mask);
    }
  if (lr == 0)
    for (int r = 0; r < 4; r++) { red[rowl + r][colg][0] = ysum[r]; red[rowl + r][colg][1] = ysq[r]; }
  __syncthreads();
  for (int r = 0; r < 4; r++) {
    float sm = red[rowl + r][0][0] + red[rowl + r][1][0];
    float sq = red[rowl + r][0][1] + red[rowl + r][1][1];
    float mean = sm * (1.f / 512.f);
    float var  = sq * (1.f / 512.f) - mean * mean;
    float rstd = rsqrtf(var + 1e-5f);
    for (int ct = 0; ct < 16; ct++) {
      int col = colg * 256 + ct * 16 + lr;
      out2[(size_t)(R0 + rowl + r) * 512 + col] =
          (acc[ct][r] - mean) * rstd * gamma[col] + beta[col];
    }
  }
}

// ---------------- k7: out1[b,e,n,s] = ctxln[b,s,n,e] ----------------
__global__ __launch_bounds__(256) void k7_out1(
    const float* __restrict__ ctxln, float* __restrict__ out1)
{
  __shared__ float tile[12][512];
  int b = blockIdx.x >> 8, n = blockIdx.x & 255;
  for (int i = threadIdx.x; i < 1536; i += 256) {
    int s = i >> 7, e4 = (i & 127) * 4;
    *(float4*)&tile[s][e4] =
        *(const float4*)(ctxln + (size_t)((b * 12 + s) * 256 + n) * 512 + e4);
  }
  __syncthreads();
  for (int e = threadIdx.x; e < 512; e += 256) {
    float vals[12];
    for (int s = 0; s < 12; s++) vals[s] = tile[s][e];
    float* gp = out1 + ((size_t)(b * 512 + e) * 256 + n) * 12;
    *(float4*)(gp)     = *(float4*)(vals);
    *(float4*)(gp + 4) = *(float4*)(vals + 4);
    *(float4*)(gp + 8) = *(float4*)(vals + 8);
  }
}

extern "C" void kernel_launch(void* const* d_in, const int* in_sizes, int n_in,
                              void* d_out, int out_size, void* d_ws, size_t ws_size,
                              hipStream_t stream) {
  const float* inQ = (const float*)d_in[0];
  const float* inK = (const float*)d_in[1];
  const float* inV = (const float*)d_in[2];
  const float* inE = (const float*)d_in[3];
  const float* Wq  = (const float*)d_in[4];
  const float* Wk  = (const float*)d_in[5];
  const float* Wv  = (const float*)d_in[6];
  const float* We  = (const float*)d_in[7];
  const float* Wo  = (const float*)d_in[8];
  const float* bo  = (const float*)d_in[9];
  const float* Wfe = (const float*)d_in[10];
  const float* bfe = (const float*)d_in[11];
  const float* go  = (const float*)d_in[12];
  const float* bto = (const float*)d_in[13];
  const float* ge  = (const float*)d_in[14];
  const float* bte = (const float*)d_in[15];

  float* out1 = (float*)d_out;                 // [2,512,256,12]
  float* out2 = out1 + 3145728;                // [2,256,256,512]

  char* ws = (char*)d_ws;
  if (ws_size < 109248512) return;             // need ~109.25 MB scratch
  float* xq   = (float*)(ws + 0);              // 12582912 B
  float* xk   = (float*)(ws + 12582912);       // 12582912 B (reused as ctxln)
  float* xv   = (float*)(ws + 25165824);       // 12582912 B (reused as ctx)
  short* Qb   = (short*)(ws + 37748736);       // 6291456 B
  short* Kb   = (short*)(ws + 44040192);
  short* Vb   = (short*)(ws + 50331648);
  short* WqT  = (short*)(ws + 56623104);       // 524288 B each
  short* WkT  = (short*)(ws + 57147392);
  short* WvT  = (short*)(ws + 57671680);
  short* WoT  = (short*)(ws + 58195968);
  short* WeT  = (short*)(ws + 58720256);       // 98304 B
  short* WfeT = (short*)(ws + 58818560);       // 98304 B
  short* ebT  = (short*)(ws + 58916864);       // 25165824 B
  short* eT   = (short*)(ws + 84082688);       // 25165824 B
  float* ctx   = xv;   // xv dead after k2
  float* ctxln = xk;   // xk dead after k2

  k0_prep<<<1024, 256, 0, stream>>>(Wq, Wk, Wv, Wo, We, Wfe, WqT, WkT, WvT, WoT, WeT, WfeT);
  k1_txpose<<<512, 256, 0, stream>>>(inQ, inK, inV, xq, xk, xv);
  k2_proj<<<dim3(48, 4, 3), 256, 0, stream>>>(xq, xk, xv, WqT, WkT, WvT, Qb, Kb, Vb);
  k3_ebx<<<1024, 256, 0, stream>>>(inE, WeT, ebT);
  k4_attn<<<dim3(4, 96, 2), 256, 0, stream>>>(Qb, Kb, Vb, ebT, eT, ctx);
  k5_ctxo<<<96, 512, 0, stream>>>(ctx, WoT, bo, xq, go, bto, ctxln);
  k6_eout<<<2048, 512, 0, stream>>>(eT, WfeT, bfe, inE, ge, bte, out2);
  k7_out1<<<512, 256, 0, stream>>>(ctxln, out1);
}